// Round 1
// baseline (461.764 us; speedup 1.0000x reference)
//
#include <hip/hip_runtime.h>
#include <hip/hip_bf16.h>

// B=16, N=256, A=64, D=256.  I = B*N = 4096 rows.
// Algebraic restructuring:
//   M[e][e']  = sum_d Wq[d][e] * Wk[d][e']          (= Wq^T @ Wk)
//   r[e']     = sum_d bq[d] * Wk[d][e']
//   u[e]      = sum_d Wq[d][e] * bk[d]
//   s0        = bq . bk
//   t[i][e']  = sum_e cc[i][e]*M[e][e'] + r[e']     (so Q.K[a] = anchor[a].t + c)
//   c[i]      = sum_e cc[i][e]*u[e] + s0
//   adj[i][a] = (anchor[i][a].t[i] + c[i]) * (1/16) + sims[i][a]
//   probs     = conditional softmax over a
//   w[i][e]   = sum_a probs[a]*anchor[i][a][e],  psum[i] = sum_a probs[a]
//   out[i][d] = sum_e w[i][e]*Wv[d][e] + bv[d]*psum[i]

#define AS 257  // anchor LDS row stride (+1 pad: conflict-free reads)

// ---------------- K1: weight prep ----------------
__global__ __launch_bounds__(256) void k1_prep(
    const float* __restrict__ Wq, const float* __restrict__ bq,
    const float* __restrict__ Wk, const float* __restrict__ bk,
    const float* __restrict__ Wv,
    float* __restrict__ M, float* __restrict__ rvec, float* __restrict__ uvec,
    float* __restrict__ s0, float* __restrict__ WvT) {
  __shared__ float colL[256];
  __shared__ float pr[256];
  __shared__ float tile[64][65];
  const int tid = threadIdx.x;
  const int bid = blockIdx.x;
  if (bid < 256) {
    // M[bid][tid] = sum_d Wq[d][bid] * Wk[d][tid]
    colL[tid] = Wq[tid * 256 + bid];
    __syncthreads();
    float acc = 0.f;
#pragma unroll 4
    for (int d = 0; d < 256; ++d) acc += colL[d] * Wk[d * 256 + tid];
    M[bid * 256 + tid] = acc;
  } else if (bid == 256) {
    colL[tid] = bq[tid];
    __syncthreads();
    float acc = 0.f;
#pragma unroll 4
    for (int d = 0; d < 256; ++d) acc += colL[d] * Wk[d * 256 + tid];
    rvec[tid] = acc;
  } else if (bid == 257) {
    colL[tid] = bk[tid];
    pr[tid] = bq[tid] * bk[tid];
    __syncthreads();
    float acc = 0.f;
#pragma unroll 4
    for (int d = 0; d < 256; ++d) acc += Wq[d * 256 + tid] * colL[d];
    uvec[tid] = acc;
    if (tid == 0) {
      float s = 0.f;
      for (int d = 0; d < 256; ++d) s += pr[d];
      s0[0] = s;
    }
  } else {
    // transpose Wv -> WvT in 64x64 tiles; tiles 0..15
    const int tb = bid - 258, bi = tb >> 2, bj = tb & 3;
#pragma unroll
    for (int k = 0; k < 16; ++k) {
      int idx = k * 256 + tid;
      int r = idx >> 6, cL = idx & 63;
      tile[r][cL] = Wv[(bi * 64 + r) * 256 + bj * 64 + cL];
    }
    __syncthreads();
#pragma unroll
    for (int k = 0; k < 16; ++k) {
      int idx = k * 256 + tid;
      int r = idx >> 6, cL = idx & 63;
      WvT[(bj * 64 + r) * 256 + bi * 64 + cL] = tile[cL][r];
    }
  }
}

// ---------------- K2: t = cc@M + r, c = cc@u + s0 (8 rows / block) ----------------
__global__ __launch_bounds__(256) void k2_proj(
    const float* __restrict__ cc, const float* __restrict__ M,
    const float* __restrict__ rvec, const float* __restrict__ uvec,
    const float* __restrict__ s0p,
    float* __restrict__ tmat, float* __restrict__ cvec) {
  __shared__ float ccT[256 * 12];  // [e][r], stride 12 (16B-aligned rows)
  __shared__ float uL[256];
  const int tid = threadIdx.x;
  const int i0 = blockIdx.x * 8;
  const float4* g4 = (const float4*)(cc + (size_t)i0 * 256);
#pragma unroll
  for (int k = 0; k < 2; ++k) {
    int f = k * 256 + tid;           // float4 index among 512
    float4 v = g4[f];
    int row = f >> 6;                // 0..7
    int e = (f & 63) << 2;
    ccT[(e + 0) * 12 + row] = v.x;
    ccT[(e + 1) * 12 + row] = v.y;
    ccT[(e + 2) * 12 + row] = v.z;
    ccT[(e + 3) * 12 + row] = v.w;
  }
  uL[tid] = uvec[tid];
  __syncthreads();
  float acc[8] = {0.f, 0.f, 0.f, 0.f, 0.f, 0.f, 0.f, 0.f};
#pragma unroll 4
  for (int e = 0; e < 256; ++e) {
    float m = M[e * 256 + tid];      // coalesced, L2-resident
    const float* crow = &ccT[e * 12];  // wave-uniform -> broadcast
#pragma unroll
    for (int r = 0; r < 8; ++r) acc[r] += crow[r] * m;
  }
  float rv = rvec[tid];
#pragma unroll
  for (int r = 0; r < 8; ++r) tmat[(size_t)(i0 + r) * 256 + tid] = acc[r] + rv;
  // c[i0+r] = cc[i0+r].u + s0
  const int r = tid >> 5, j = tid & 31;
  float pc = 0.f;
#pragma unroll
  for (int k = 0; k < 8; ++k) pc += ccT[(j + 32 * k) * 12 + r] * uL[j + 32 * k];
  for (int off = 16; off >= 1; off >>= 1) pc += __shfl_xor(pc, off, 32);
  if (j == 0) cvec[i0 + r] = pc + s0p[0];
}

// ---------------- K3: main attention (one block per (b,n)) ----------------
__global__ __launch_bounds__(256) void k3_attn(
    const float* __restrict__ anchor, const float* __restrict__ sims,
    const float* __restrict__ tmat, const float* __restrict__ cvec,
    float* __restrict__ wout, float* __restrict__ psum) {
  __shared__ float aL[64 * AS];
  __shared__ float tL[256];
  __shared__ float partial[4][64];
  __shared__ float probsL[64];
  __shared__ float psh;
  const int i = blockIdx.x;
  const int tid = threadIdx.x;
  // stage anchor slice [64][256] fp32 (64 KB) via float4 loads
  const float4* g4 = (const float4*)(anchor + (size_t)i * 16384);
#pragma unroll
  for (int k = 0; k < 16; ++k) {
    int f = k * 256 + tid;           // float4 index among 4096
    float4 v = g4[f];
    int row = f >> 6;
    int c4 = (f & 63) << 2;
    float* dst = &aL[row * AS + c4];
    dst[0] = v.x; dst[1] = v.y; dst[2] = v.z; dst[3] = v.w;
  }
  tL[tid] = tmat[(size_t)i * 256 + tid];
  __syncthreads();
  // scores: lane a = tid&63 does 64-chunk (tid>>6) of dot(anchor[a], t)
  const int lane = tid & 63, w = tid >> 6;
  {
    const float* a0 = &aL[lane * AS + w * 64];
    const float* t0 = &tL[w * 64];
    float s = 0.f;
#pragma unroll
    for (int j = 0; j < 64; ++j) s += a0[j] * t0[j];
    partial[w][lane] = s;
  }
  __syncthreads();
  if (tid < 64) {
    float adj = partial[0][tid] + partial[1][tid] + partial[2][tid] + partial[3][tid];
    adj = (adj + cvec[i]) * 0.0625f + sims[(size_t)i * 64 + tid];
    float ssum = adj, smax = adj;
    for (int off = 32; off >= 1; off >>= 1) {
      ssum += __shfl_xor(ssum, off, 64);
      smax = fmaxf(smax, __shfl_xor(smax, off, 64));
    }
    float p;
    if (ssum != 0.f) {
      p = expf(adj - smax);
      float z = p;
      for (int off = 32; off >= 1; off >>= 1) z += __shfl_xor(z, off, 64);
      p = p / z;
    } else {
      p = adj;  // pass-through row
    }
    float ps = p;
    for (int off = 32; off >= 1; off >>= 1) ps += __shfl_xor(ps, off, 64);
    probsL[tid] = p;
    if (tid == 0) psh = ps;
  }
  __syncthreads();
  // weighted sum over anchors: thread e
  float acc = 0.f;
#pragma unroll
  for (int a = 0; a < 64; ++a) acc += probsL[a] * aL[a * AS + tid];
  wout[(size_t)i * 256 + tid] = acc;
  if (tid == 0) psum[i] = psh;
}

// ---------------- K4: out = w@WvT + bv*psum (8 rows / block) ----------------
__global__ __launch_bounds__(256) void k4_out(
    const float* __restrict__ wmat, const float* __restrict__ WvT,
    const float* __restrict__ bv, const float* __restrict__ psum,
    float* __restrict__ out) {
  __shared__ float wT[256 * 12];
  __shared__ float psL[8];
  const int tid = threadIdx.x;
  const int i0 = blockIdx.x * 8;
  const float4* g4 = (const float4*)(wmat + (size_t)i0 * 256);
#pragma unroll
  for (int k = 0; k < 2; ++k) {
    int f = k * 256 + tid;
    float4 v = g4[f];
    int row = f >> 6;
    int e = (f & 63) << 2;
    wT[(e + 0) * 12 + row] = v.x;
    wT[(e + 1) * 12 + row] = v.y;
    wT[(e + 2) * 12 + row] = v.z;
    wT[(e + 3) * 12 + row] = v.w;
  }
  if (tid < 8) psL[tid] = psum[i0 + tid];
  __syncthreads();
  float acc[8] = {0.f, 0.f, 0.f, 0.f, 0.f, 0.f, 0.f, 0.f};
#pragma unroll 4
  for (int e = 0; e < 256; ++e) {
    float m = WvT[e * 256 + tid];
    const float* wr = &wT[e * 12];
#pragma unroll
    for (int r = 0; r < 8; ++r) acc[r] += wr[r] * m;
  }
  float b = bv[tid];
#pragma unroll
  for (int r = 0; r < 8; ++r)
    out[(size_t)(i0 + r) * 256 + tid] = acc[r] + b * psL[r];
}

extern "C" void kernel_launch(void* const* d_in, const int* in_sizes, int n_in,
                              void* d_out, int out_size, void* d_ws, size_t ws_size,
                              hipStream_t stream) {
  const float* cc     = (const float*)d_in[0];  // [16,256,256]
  const float* anchor = (const float*)d_in[1];  // [16,256,64,256]
  const float* sims   = (const float*)d_in[2];  // [16,256,64]
  const float* Wq     = (const float*)d_in[3];
  const float* bq     = (const float*)d_in[4];
  const float* Wk     = (const float*)d_in[5];
  const float* bk     = (const float*)d_in[6];
  const float* Wv     = (const float*)d_in[7];
  const float* bv     = (const float*)d_in[8];
  float* out = (float*)d_out;
  float* ws  = (float*)d_ws;

  float* M    = ws;                 // 65536
  float* WvT  = ws + 65536;         // 65536
  float* rvec = ws + 131072;        // 256
  float* uvec = ws + 131328;        // 256
  float* s0   = ws + 131584;        // 256 (pad)
  float* cvec = ws + 131840;        // 4096
  float* psum = ws + 135936;        // 4096
  float* tmat = ws + 140032;        // 1048576
  float* wmat = tmat + 1048576;     // 1048576   (total ~8.9 MB)

  k1_prep<<<274, 256, 0, stream>>>(Wq, bq, Wk, bk, Wv, M, rvec, uvec, s0, WvT);
  k2_proj<<<512, 256, 0, stream>>>(cc, M, rvec, uvec, s0, tmat, cvec);
  k3_attn<<<4096, 256, 0, stream>>>(anchor, sims, tmat, cvec, wmat, psum);
  k4_out<<<512, 256, 0, stream>>>(wmat, WvT, bv, psum, out);
}

// Round 2
// 461.017 us; speedup vs baseline: 1.0016x; 1.0016x over previous
//
#include <hip/hip_runtime.h>
#include <hip/hip_bf16.h>

// B=16, N=256, A=64, D=256.  I = B*N = 4096 rows.
// Algebra:
//   M = Wq^T@Wk, r = bq@Wk, u = Wq^T@bk, s0 = bq.bk
//   t[i] = cc[i]@M + r,  c[i] = cc[i].u + s0
//   adj[i][a] = (anchor[i][a].t[i] + c[i])/16 + sims[i][a]
//   probs = conditional softmax; w[i] = sum_a p[a]*anchor[i][a]; psum = sum p
//   out[i][d] = sum_e w[i][e]*Wv[d][e] + bv[d]*psum[i]

// ---------------- K1: weight prep ----------------
__global__ __launch_bounds__(256) void k1_prep(
    const float* __restrict__ Wq, const float* __restrict__ bq,
    const float* __restrict__ Wk, const float* __restrict__ bk,
    const float* __restrict__ Wv,
    float* __restrict__ M, float* __restrict__ rvec, float* __restrict__ uvec,
    float* __restrict__ s0, float* __restrict__ WvT) {
  __shared__ float colL[256];
  __shared__ float pr[256];
  __shared__ float tile[64][65];
  const int tid = threadIdx.x;
  const int bid = blockIdx.x;
  if (bid < 256) {
    colL[tid] = Wq[tid * 256 + bid];
    __syncthreads();
    float acc = 0.f;
#pragma unroll 4
    for (int d = 0; d < 256; ++d) acc += colL[d] * Wk[d * 256 + tid];
    M[bid * 256 + tid] = acc;
  } else if (bid == 256) {
    colL[tid] = bq[tid];
    __syncthreads();
    float acc = 0.f;
#pragma unroll 4
    for (int d = 0; d < 256; ++d) acc += colL[d] * Wk[d * 256 + tid];
    rvec[tid] = acc;
  } else if (bid == 257) {
    colL[tid] = bk[tid];
    pr[tid] = bq[tid] * bk[tid];
    __syncthreads();
    float acc = 0.f;
#pragma unroll 4
    for (int d = 0; d < 256; ++d) acc += Wq[d * 256 + tid] * colL[d];
    uvec[tid] = acc;
    if (tid == 0) {
      float s = 0.f;
      for (int d = 0; d < 256; ++d) s += pr[d];
      s0[0] = s;
    }
  } else {
    const int tb = bid - 258, bi = tb >> 2, bj = tb & 3;
#pragma unroll
    for (int k = 0; k < 16; ++k) {
      int idx = k * 256 + tid;
      int r = idx >> 6, cL = idx & 63;
      tile[r][cL] = Wv[(bi * 64 + r) * 256 + bj * 64 + cL];
    }
    __syncthreads();
#pragma unroll
    for (int k = 0; k < 16; ++k) {
      int idx = k * 256 + tid;
      int r = idx >> 6, cL = idx & 63;
      WvT[(bj * 64 + r) * 256 + bi * 64 + cL] = tile[cL][r];
    }
  }
}

// ---------------- K2: t = cc@M + r, c = cc@u + s0 (8 rows / block) ----------------
__global__ __launch_bounds__(256) void k2_proj(
    const float* __restrict__ cc, const float* __restrict__ M,
    const float* __restrict__ rvec, const float* __restrict__ uvec,
    const float* __restrict__ s0p,
    float* __restrict__ tmat, float* __restrict__ cvec) {
  __shared__ __align__(16) float ccT[256 * 8];  // [e][r], stride 8 -> b128 reads
  __shared__ float uL[256];
  const int tid = threadIdx.x;
  const int i0 = blockIdx.x * 8;
  const float4* g4 = (const float4*)(cc + (size_t)i0 * 256);
#pragma unroll
  for (int k = 0; k < 2; ++k) {
    int f = k * 256 + tid;
    float4 v = g4[f];
    int row = f >> 6;
    int e = (f & 63) << 2;
    ccT[(e + 0) * 8 + row] = v.x;
    ccT[(e + 1) * 8 + row] = v.y;
    ccT[(e + 2) * 8 + row] = v.z;
    ccT[(e + 3) * 8 + row] = v.w;
  }
  uL[tid] = uvec[tid];
  __syncthreads();
  float acc[8] = {0.f, 0.f, 0.f, 0.f, 0.f, 0.f, 0.f, 0.f};
#pragma unroll 4
  for (int e = 0; e < 256; ++e) {
    float m = M[e * 256 + tid];                     // coalesced, L2-resident
    const float4* cr = (const float4*)(ccT + e * 8);  // wave-uniform broadcast
    float4 c0 = cr[0], c1 = cr[1];
    acc[0] += c0.x * m; acc[1] += c0.y * m; acc[2] += c0.z * m; acc[3] += c0.w * m;
    acc[4] += c1.x * m; acc[5] += c1.y * m; acc[6] += c1.z * m; acc[7] += c1.w * m;
  }
  float rv = rvec[tid];
#pragma unroll
  for (int r = 0; r < 8; ++r) tmat[(size_t)(i0 + r) * 256 + tid] = acc[r] + rv;
  // c[i0+r] = cc[i0+r].u + s0
  const int r = tid >> 5, j = tid & 31;
  float pc = 0.f;
#pragma unroll
  for (int k = 0; k < 8; ++k) pc += ccT[(j + 32 * k) * 8 + r] * uL[j + 32 * k];
  for (int off = 16; off >= 1; off >>= 1) pc += __shfl_xor(pc, off, 32);
  if (j == 0) cvec[i0 + r] = pc + s0p[0];
}

// ---------------- K3: main attention, register-staged (one block per (b,n)) ----
__global__ __launch_bounds__(256) void k3_attn(
    const float* __restrict__ anchor, const float* __restrict__ sims,
    const float* __restrict__ tmat, const float* __restrict__ cvec,
    float* __restrict__ wout, float* __restrict__ psum) {
  __shared__ float sL[64];
  __shared__ float pL[64];
  __shared__ __align__(16) float pW[4 * 256];
  __shared__ float psh;
  const int i = blockIdx.x;
  const int tid = threadIdx.x;
  const int lane = tid & 63, w = tid >> 6;

  // Register-stage this row's anchor slice: thread holds rows k*4+w, cols 4*lane..4*lane+3.
  const float4* g4 = (const float4*)(anchor + (size_t)i * 16384);
  float4 v[16];
#pragma unroll
  for (int k = 0; k < 16; ++k) v[k] = g4[k * 256 + tid];
  const float4 t4 = ((const float4*)(tmat + (size_t)i * 256))[lane];

  // scores: per-k 4 FMA then 64-lane butterfly reduce
#pragma unroll
  for (int k = 0; k < 16; ++k) {
    float s = v[k].x * t4.x + v[k].y * t4.y + v[k].z * t4.z + v[k].w * t4.w;
#pragma unroll
    for (int off = 32; off >= 1; off >>= 1) s += __shfl_xor(s, off, 64);
    if (lane == 0) sL[k * 4 + w] = s;
  }
  __syncthreads();
  if (tid < 64) {
    float adj = (sL[tid] + cvec[i]) * 0.0625f + sims[(size_t)i * 64 + tid];
    float ssum = adj, smax = adj;
    for (int off = 32; off >= 1; off >>= 1) {
      ssum += __shfl_xor(ssum, off, 64);
      smax = fmaxf(smax, __shfl_xor(smax, off, 64));
    }
    float p;
    if (ssum != 0.f) {
      p = expf(adj - smax);
      float z = p;
      for (int off = 32; off >= 1; off >>= 1) z += __shfl_xor(z, off, 64);
      p = p / z;
    } else {
      p = adj;  // pass-through row
    }
    float ps = p;
    for (int off = 32; off >= 1; off >>= 1) ps += __shfl_xor(ps, off, 64);
    pL[tid] = p;
    if (tid == 0) psh = ps;
  }
  __syncthreads();
  // weighted anchor sum from registers; prob via LDS broadcast
  float4 acc = {0.f, 0.f, 0.f, 0.f};
#pragma unroll
  for (int k = 0; k < 16; ++k) {
    float p = pL[k * 4 + w];
    acc.x += p * v[k].x; acc.y += p * v[k].y;
    acc.z += p * v[k].z; acc.w += p * v[k].w;
  }
  ((float4*)(pW + w * 256))[lane] = acc;
  __syncthreads();
  float val = pW[tid] + pW[256 + tid] + pW[512 + tid] + pW[768 + tid];
  wout[(size_t)i * 256 + tid] = val;
  if (tid == 0) psum[i] = psh;
}

// ---------------- K4: out = w@WvT + bv*psum (8 rows / block) ----------------
__global__ __launch_bounds__(256) void k4_out(
    const float* __restrict__ wmat, const float* __restrict__ WvT,
    const float* __restrict__ bv, const float* __restrict__ psum,
    float* __restrict__ out) {
  __shared__ __align__(16) float wT[256 * 8];
  __shared__ float psL[8];
  const int tid = threadIdx.x;
  const int i0 = blockIdx.x * 8;
  const float4* g4 = (const float4*)(wmat + (size_t)i0 * 256);
#pragma unroll
  for (int k = 0; k < 2; ++k) {
    int f = k * 256 + tid;
    float4 v = g4[f];
    int row = f >> 6;
    int e = (f & 63) << 2;
    wT[(e + 0) * 8 + row] = v.x;
    wT[(e + 1) * 8 + row] = v.y;
    wT[(e + 2) * 8 + row] = v.z;
    wT[(e + 3) * 8 + row] = v.w;
  }
  if (tid < 8) psL[tid] = psum[i0 + tid];
  __syncthreads();
  float acc[8] = {0.f, 0.f, 0.f, 0.f, 0.f, 0.f, 0.f, 0.f};
#pragma unroll 4
  for (int e = 0; e < 256; ++e) {
    float m = WvT[e * 256 + tid];
    const float4* wr = (const float4*)(wT + e * 8);
    float4 c0 = wr[0], c1 = wr[1];
    acc[0] += c0.x * m; acc[1] += c0.y * m; acc[2] += c0.z * m; acc[3] += c0.w * m;
    acc[4] += c1.x * m; acc[5] += c1.y * m; acc[6] += c1.z * m; acc[7] += c1.w * m;
  }
  float b = bv[tid];
#pragma unroll
  for (int r = 0; r < 8; ++r)
    out[(size_t)(i0 + r) * 256 + tid] = acc[r] + b * psL[r];
}

extern "C" void kernel_launch(void* const* d_in, const int* in_sizes, int n_in,
                              void* d_out, int out_size, void* d_ws, size_t ws_size,
                              hipStream_t stream) {
  const float* cc     = (const float*)d_in[0];  // [16,256,256]
  const float* anchor = (const float*)d_in[1];  // [16,256,64,256]
  const float* sims   = (const float*)d_in[2];  // [16,256,64]
  const float* Wq     = (const float*)d_in[3];
  const float* bq     = (const float*)d_in[4];
  const float* Wk     = (const float*)d_in[5];
  const float* bk     = (const float*)d_in[6];
  const float* Wv     = (const float*)d_in[7];
  const float* bv     = (const float*)d_in[8];
  float* out = (float*)d_out;
  float* ws  = (float*)d_ws;

  float* M    = ws;                 // 65536
  float* WvT  = ws + 65536;         // 65536
  float* rvec = ws + 131072;        // 256
  float* uvec = ws + 131328;        // 256
  float* s0   = ws + 131584;        // 256 (pad)
  float* cvec = ws + 131840;        // 4096
  float* psum = ws + 135936;        // 4096
  float* tmat = ws + 140032;        // 1048576
  float* wmat = tmat + 1048576;     // 1048576

  k1_prep<<<274, 256, 0, stream>>>(Wq, bq, Wk, bk, Wv, M, rvec, uvec, s0, WvT);
  k2_proj<<<512, 256, 0, stream>>>(cc, M, rvec, uvec, s0, tmat, cvec);
  k3_attn<<<4096, 256, 0, stream>>>(anchor, sims, tmat, cvec, wmat, psum);
  k4_out<<<512, 256, 0, stream>>>(wmat, WvT, bv, psum, out);
}

// Round 3
// 414.590 us; speedup vs baseline: 1.1138x; 1.1120x over previous
//
#include <hip/hip_runtime.h>
#include <hip/hip_bf16.h>

// B=16, N=256, A=64, D=256.  I = B*N = 4096 rows.
// Algebra:
//   M = Wq^T@Wk, r = bq@Wk, u = Wq^T@bk, s0 = bq.bk
//   t[i] = cc[i]@M + r,  c[i] = cc[i].u + s0
//   adj[i][a] = (anchor[i][a].t[i] + c[i])/16 + sims[i][a]
//   probs = conditional softmax; w[i] = sum_a p[a]*anchor[i][a]; psum = sum p
//   out[i][d] = sum_e w[i][e]*Wv[d][e] + bv[d]*psum[i]

typedef float f4 __attribute__((ext_vector_type(4)));

__device__ __forceinline__ float bcast_lane(float x, int lane) {
  return __int_as_float(__builtin_amdgcn_readlane(__float_as_int(x), lane));
}

// ---------------- K1: weight prep ----------------
__global__ __launch_bounds__(256) void k1_prep(
    const float* __restrict__ Wq, const float* __restrict__ bq,
    const float* __restrict__ Wk, const float* __restrict__ bk,
    const float* __restrict__ Wv,
    float* __restrict__ M, float* __restrict__ rvec, float* __restrict__ uvec,
    float* __restrict__ s0, float* __restrict__ WvT) {
  __shared__ float colL[256];
  __shared__ float pr[256];
  __shared__ float tile[64][65];
  const int tid = threadIdx.x;
  const int bid = blockIdx.x;
  if (bid < 256) {
    colL[tid] = Wq[tid * 256 + bid];
    __syncthreads();
    float acc = 0.f;
#pragma unroll 4
    for (int d = 0; d < 256; ++d) acc += colL[d] * Wk[d * 256 + tid];
    M[bid * 256 + tid] = acc;
  } else if (bid == 256) {
    colL[tid] = bq[tid];
    __syncthreads();
    float acc = 0.f;
#pragma unroll 4
    for (int d = 0; d < 256; ++d) acc += colL[d] * Wk[d * 256 + tid];
    rvec[tid] = acc;
  } else if (bid == 257) {
    colL[tid] = bk[tid];
    pr[tid] = bq[tid] * bk[tid];
    __syncthreads();
    float acc = 0.f;
#pragma unroll 4
    for (int d = 0; d < 256; ++d) acc += Wq[d * 256 + tid] * colL[d];
    uvec[tid] = acc;
    if (tid == 0) {
      float s = 0.f;
      for (int d = 0; d < 256; ++d) s += pr[d];
      s0[0] = s;
    }
  } else {
    const int tb = bid - 258, bi = tb >> 2, bj = tb & 3;
#pragma unroll
    for (int k = 0; k < 16; ++k) {
      int idx = k * 256 + tid;
      int r = idx >> 6, cL = idx & 63;
      tile[r][cL] = Wv[(bi * 64 + r) * 256 + bj * 64 + cL];
    }
    __syncthreads();
#pragma unroll
    for (int k = 0; k < 16; ++k) {
      int idx = k * 256 + tid;
      int r = idx >> 6, cL = idx & 63;
      WvT[(bj * 64 + r) * 256 + bi * 64 + cL] = tile[cL][r];
    }
  }
}

// ---------------- K2: t = cc@M + r, c = cc@u + s0 (8 rows / block) ------------
// Wave w covers e in [64w,64w+64); thread covers cols 4L..4L+3 for all 8 rows.
// cc chunk register-staged; per-e broadcast via v_readlane (no in-loop LDS).
__global__ __launch_bounds__(256) void k2_proj(
    const float* __restrict__ cc, const float* __restrict__ M,
    const float* __restrict__ rvec, const float* __restrict__ uvec,
    const float* __restrict__ s0p,
    float* __restrict__ tmat, float* __restrict__ cvec) {
  __shared__ __align__(16) float pOut[4][8][256];  // 32 KB partials
  __shared__ float cpart[4][8];
  const int tid = threadIdx.x;
  const int w = tid >> 6, L = tid & 63;
  const int i0 = blockIdx.x * 8;
  const int e0 = w * 64;
  float ccreg[8];
#pragma unroll
  for (int r = 0; r < 8; ++r) ccreg[r] = cc[(size_t)(i0 + r) * 256 + e0 + L];
  float uvl = uvec[e0 + L];
  f4 acc[8] = {};
#pragma unroll 8
  for (int ee = 0; ee < 64; ++ee) {
    f4 m = *(const f4*)(M + (size_t)(e0 + ee) * 256 + 4 * L);
#pragma unroll
    for (int r = 0; r < 8; ++r) {
      float cv = bcast_lane(ccreg[r], ee);
      acc[r].x += cv * m.x; acc[r].y += cv * m.y;
      acc[r].z += cv * m.z; acc[r].w += cv * m.w;
    }
  }
#pragma unroll
  for (int r = 0; r < 8; ++r) *(f4*)&pOut[w][r][4 * L] = acc[r];
  // cvec partials: wave-local dot with u
#pragma unroll
  for (int r = 0; r < 8; ++r) {
    float pc = ccreg[r] * uvl;
#pragma unroll
    for (int off = 32; off >= 1; off >>= 1) pc += __shfl_xor(pc, off, 64);
    if (L == 0) cpart[w][r] = pc;
  }
  __syncthreads();
  float rv = rvec[tid];
#pragma unroll
  for (int r = 0; r < 8; ++r) {
    float s = pOut[0][r][tid] + pOut[1][r][tid] + pOut[2][r][tid] + pOut[3][r][tid];
    tmat[(size_t)(i0 + r) * 256 + tid] = s + rv;
  }
  if (tid < 8)
    cvec[i0 + tid] = cpart[0][tid] + cpart[1][tid] + cpart[2][tid] + cpart[3][tid] + s0p[0];
}

// ---------------- K3: main attention, register-staged (one block per (b,n)) ----
__global__ __launch_bounds__(256) void k3_attn(
    const float* __restrict__ anchor, const float* __restrict__ sims,
    const float* __restrict__ tmat, const float* __restrict__ cvec,
    float* __restrict__ wout, float* __restrict__ psum) {
  __shared__ float sL[64];
  __shared__ float pL[64];
  __shared__ __align__(16) float pW[4 * 256];
  __shared__ float psh;
  const int i = blockIdx.x;
  const int tid = threadIdx.x;
  const int lane = tid & 63, w = tid >> 6;

  // Register-stage anchor slice: thread holds rows k*4+w, cols 4*lane..4*lane+3.
  // Nontemporal: zero-reuse 256 MB stream — don't thrash L2.
  const f4* g4 = (const f4*)(anchor + (size_t)i * 16384);
  f4 v[16];
#pragma unroll
  for (int k = 0; k < 16; ++k) v[k] = __builtin_nontemporal_load(g4 + k * 256 + tid);
  const f4 t4 = ((const f4*)(tmat + (size_t)i * 256))[lane];

  // scores: per-k 4 FMA then 64-lane butterfly reduce
#pragma unroll
  for (int k = 0; k < 16; ++k) {
    float s = v[k].x * t4.x + v[k].y * t4.y + v[k].z * t4.z + v[k].w * t4.w;
#pragma unroll
    for (int off = 32; off >= 1; off >>= 1) s += __shfl_xor(s, off, 64);
    if (lane == 0) sL[k * 4 + w] = s;
  }
  __syncthreads();
  if (tid < 64) {
    float adj = (sL[tid] + cvec[i]) * 0.0625f + sims[(size_t)i * 64 + tid];
    float ssum = adj, smax = adj;
    for (int off = 32; off >= 1; off >>= 1) {
      ssum += __shfl_xor(ssum, off, 64);
      smax = fmaxf(smax, __shfl_xor(smax, off, 64));
    }
    float p;
    if (ssum != 0.f) {
      p = expf(adj - smax);
      float z = p;
      for (int off = 32; off >= 1; off >>= 1) z += __shfl_xor(z, off, 64);
      p = p / z;
    } else {
      p = adj;  // pass-through row
    }
    float ps = p;
    for (int off = 32; off >= 1; off >>= 1) ps += __shfl_xor(ps, off, 64);
    pL[tid] = p;
    if (tid == 0) psh = ps;
  }
  __syncthreads();
  // weighted anchor sum from registers; prob via LDS broadcast
  f4 acc = {0.f, 0.f, 0.f, 0.f};
#pragma unroll
  for (int k = 0; k < 16; ++k) {
    float p = pL[k * 4 + w];
    acc.x += p * v[k].x; acc.y += p * v[k].y;
    acc.z += p * v[k].z; acc.w += p * v[k].w;
  }
  *(f4*)(pW + w * 256 + 4 * lane) = acc;
  __syncthreads();
  float val = pW[tid] + pW[256 + tid] + pW[512 + tid] + pW[768 + tid];
  wout[(size_t)i * 256 + tid] = val;
  if (tid == 0) psum[i] = psh;
}

// ---------------- K4: out = w@WvT + bv*psum (8 rows / block) ------------------
__global__ __launch_bounds__(256) void k4_out(
    const float* __restrict__ wmat, const float* __restrict__ WvT,
    const float* __restrict__ bv, const float* __restrict__ psum,
    float* __restrict__ out) {
  __shared__ __align__(16) float pOut[4][8][256];
  const int tid = threadIdx.x;
  const int w = tid >> 6, L = tid & 63;
  const int i0 = blockIdx.x * 8;
  const int e0 = w * 64;
  float wreg[8];
#pragma unroll
  for (int r = 0; r < 8; ++r) wreg[r] = wmat[(size_t)(i0 + r) * 256 + e0 + L];
  f4 acc[8] = {};
#pragma unroll 8
  for (int ee = 0; ee < 64; ++ee) {
    f4 m = *(const f4*)(WvT + (size_t)(e0 + ee) * 256 + 4 * L);
#pragma unroll
    for (int r = 0; r < 8; ++r) {
      float cv = bcast_lane(wreg[r], ee);
      acc[r].x += cv * m.x; acc[r].y += cv * m.y;
      acc[r].z += cv * m.z; acc[r].w += cv * m.w;
    }
  }
#pragma unroll
  for (int r = 0; r < 8; ++r) *(f4*)&pOut[w][r][4 * L] = acc[r];
  __syncthreads();
  float b = bv[tid];
#pragma unroll
  for (int r = 0; r < 8; ++r) {
    float s = pOut[0][r][tid] + pOut[1][r][tid] + pOut[2][r][tid] + pOut[3][r][tid];
    out[(size_t)(i0 + r) * 256 + tid] = s + b * psum[i0 + r];
  }
}

extern "C" void kernel_launch(void* const* d_in, const int* in_sizes, int n_in,
                              void* d_out, int out_size, void* d_ws, size_t ws_size,
                              hipStream_t stream) {
  const float* cc     = (const float*)d_in[0];  // [16,256,256]
  const float* anchor = (const float*)d_in[1];  // [16,256,64,256]
  const float* sims   = (const float*)d_in[2];  // [16,256,64]
  const float* Wq     = (const float*)d_in[3];
  const float* bq     = (const float*)d_in[4];
  const float* Wk     = (const float*)d_in[5];
  const float* bk     = (const float*)d_in[6];
  const float* Wv     = (const float*)d_in[7];
  const float* bv     = (const float*)d_in[8];
  float* out = (float*)d_out;
  float* ws  = (float*)d_ws;

  float* M    = ws;                 // 65536
  float* WvT  = ws + 65536;         // 65536
  float* rvec = ws + 131072;        // 256
  float* uvec = ws + 131328;        // 256
  float* s0   = ws + 131584;        // 256 (pad)
  float* cvec = ws + 131840;        // 4096
  float* psum = ws + 135936;        // 4096
  float* tmat = ws + 140032;        // 1048576
  float* wmat = tmat + 1048576;     // 1048576

  k1_prep<<<274, 256, 0, stream>>>(Wq, bq, Wk, bk, Wv, M, rvec, uvec, s0, WvT);
  k2_proj<<<512, 256, 0, stream>>>(cc, M, rvec, uvec, s0, tmat, cvec);
  k3_attn<<<4096, 256, 0, stream>>>(anchor, sims, tmat, cvec, wmat, psum);
  k4_out<<<512, 256, 0, stream>>>(wmat, WvT, bv, psum, out);
}